// Round 15
// baseline (367.921 us; speedup 1.0000x reference)
//
#include <hip/hip_runtime.h>

// ---------------------------------------------------------------------------
// ResidualAttentionBlock: LN1 -> QKV -> MHA(12 heads, Dh=64) -> out+res ->
//                         LN2 -> FC(4E)+QuickGELU -> proj+res
// R19: out/proj GEMM TN 64->96 (wave-tile 64x48, NI=3). The one clean
//      untested tile point: 56KB LDS -> 2 blocks/CU, grid (64,8)=512 blocks
//      = EXACTLY one round (R13b's TN=128 test was confounded by 1.5/2.25-
//      round imbalance on every GEMM). LDS-read bytes/FLOP -23%, 12 MFMA/ks
//      vs 8. Rest = R18 verbatim (366.0us best: head fusion, fused coalesced
//      V-epilogue replacing vtrans, R9b QKV/FC tiles, R13b flash 95.5-96.6us
//      stable x8 runs, FETCH 18.5MB).
// ---------------------------------------------------------------------------

#define E 768
#define LSEQ 2048
#define PW 40

typedef short bfrag __attribute__((ext_vector_type(8)));   // 8 bf16 = 4 VGPRs
typedef float facc  __attribute__((ext_vector_type(4)));   // 4 fp32 acc

__device__ __forceinline__ unsigned short f2bf(float f) {
  unsigned int u = __float_as_uint(f);
  u = (u + 0x7fffu + ((u >> 16) & 1u)) >> 16;   // RNE
  return (unsigned short)u;
}

__device__ __forceinline__ facc mfma16(bfrag a, bfrag b, facc c) {
  return __builtin_amdgcn_mfma_f32_16x16x32_bf16(a, b, c, 0, 0, 0);
}

__device__ __forceinline__ void gl2lds16(const void* g, void* l) {
  __builtin_amdgcn_global_load_lds((__attribute__((address_space(1))) void*)g,
                                   (__attribute__((address_space(3))) void*)l,
                                   16, 0, 0);
}

// --------------------------- fused head: LN1 + fp32->bf16 weight cast -------
// blocks [0,2048): LN1 rows (4 rows/block). blocks [2048,8960): weight cast,
// b2 = b-2048: [0,1728) w_qkv, [1728,2304) w_out, [2304,4608) w_fc,
// [4608,6912) w_proj. Independent work, both BW-bound -> co-scheduled.
__global__ __launch_bounds__(256) void head_k(const float* __restrict__ x,
                                              const float* __restrict__ lw,
                                              const float* __restrict__ lb,
                                              unsigned short* __restrict__ hout,
                                              const float* __restrict__ wq,
                                              const float* __restrict__ wo,
                                              const float* __restrict__ wf,
                                              const float* __restrict__ wp,
                                              unsigned short* __restrict__ d0,
                                              unsigned short* __restrict__ d1,
                                              unsigned short* __restrict__ d2,
                                              unsigned short* __restrict__ d3) {
  int b = blockIdx.x;
  if (b < 2048) {
    // ---- LN1 path ----
    int row = b * 4 + (threadIdx.x >> 6);
    int lane = threadIdx.x & 63;
    const float* xr = x + row * E;
    float4 v[3];
    float s = 0.f, ss = 0.f;
#pragma unroll
    for (int i = 0; i < 3; ++i) {
      v[i] = *(const float4*)(xr + i * 256 + lane * 4);
      s += v[i].x + v[i].y + v[i].z + v[i].w;
      ss += v[i].x * v[i].x + v[i].y * v[i].y + v[i].z * v[i].z + v[i].w * v[i].w;
    }
#pragma unroll
    for (int m = 32; m; m >>= 1) { s += __shfl_xor(s, m); ss += __shfl_xor(ss, m); }
    float mu = s * (1.f / E);
    float rstd = rsqrtf(ss * (1.f / E) - mu * mu + 1e-5f);
#pragma unroll
    for (int i = 0; i < 3; ++i) {
      int c = i * 256 + lane * 4;
      float4 wv = *(const float4*)(lw + c);
      float4 bv = *(const float4*)(lb + c);
      float y0 = (v[i].x - mu) * rstd * wv.x + bv.x;
      float y1 = (v[i].y - mu) * rstd * wv.y + bv.y;
      float y2 = (v[i].z - mu) * rstd * wv.z + bv.z;
      float y3 = (v[i].w - mu) * rstd * wv.w + bv.w;
      uint2 o;
      o.x = (unsigned)f2bf(y0) | ((unsigned)f2bf(y1) << 16);
      o.y = (unsigned)f2bf(y2) | ((unsigned)f2bf(y3) << 16);
      *(uint2*)(hout + row * E + c) = o;
    }
  } else {
    // ---- weight-cast path ----
    int b2 = b - 2048;
    const float* s; unsigned short* d; int off;
    if (b2 < 1728)      { s = wq; d = d0; off = b2; }
    else if (b2 < 2304) { s = wo; d = d1; off = b2 - 1728; }
    else if (b2 < 4608) { s = wf; d = d2; off = b2 - 2304; }
    else                { s = wp; d = d3; off = b2 - 4608; }
    int i = (off * 256 + threadIdx.x) * 4;
    float4 v = *(const float4*)(s + i);
    uint2 u;
    u.x = (unsigned)f2bf(v.x) | ((unsigned)f2bf(v.y) << 16);
    u.y = (unsigned)f2bf(v.z) | ((unsigned)f2bf(v.w) << 16);
    *(uint2*)(d + i) = u;
  }
}

// --------------------------- LayerNorm (fp32 in, bf16 out) — LN2 ------------
__global__ __launch_bounds__(256) void ln_bf16_k(const float* __restrict__ x,
                                                 const float* __restrict__ w,
                                                 const float* __restrict__ b,
                                                 unsigned short* __restrict__ out) {
  int row = blockIdx.x * 4 + (threadIdx.x >> 6);
  int lane = threadIdx.x & 63;
  const float* xr = x + row * E;
  float4 v[3];
  float s = 0.f, ss = 0.f;
#pragma unroll
  for (int i = 0; i < 3; ++i) {
    v[i] = *(const float4*)(xr + i * 256 + lane * 4);
    s += v[i].x + v[i].y + v[i].z + v[i].w;
    ss += v[i].x * v[i].x + v[i].y * v[i].y + v[i].z * v[i].z + v[i].w * v[i].w;
  }
#pragma unroll
  for (int m = 32; m; m >>= 1) { s += __shfl_xor(s, m); ss += __shfl_xor(ss, m); }
  float mu = s * (1.f / E);
  float rstd = rsqrtf(ss * (1.f / E) - mu * mu + 1e-5f);
#pragma unroll
  for (int i = 0; i < 3; ++i) {
    int c = i * 256 + lane * 4;
    float4 wv = *(const float4*)(w + c);
    float4 bv = *(const float4*)(b + c);
    float y0 = (v[i].x - mu) * rstd * wv.x + bv.x;
    float y1 = (v[i].y - mu) * rstd * wv.y + bv.y;
    float y2 = (v[i].z - mu) * rstd * wv.z + bv.z;
    float y3 = (v[i].w - mu) * rstd * wv.w + bv.w;
    uint2 o;
    o.x = (unsigned)f2bf(y0) | ((unsigned)f2bf(y1) << 16);
    o.y = (unsigned)f2bf(y2) | ((unsigned)f2bf(y3) << 16);
    *(uint2*)(out + row * E + c) = o;
  }
}

// --------------------------- GEMM: C[M,N] = A[M,K] * W[N,K]^T + epilogue ----
// TM=128, BK=64, double-buffered LDS, 2-phase pipeline. MODE 3 (QKV):
// V-third blocks (n0>=1536, block-uniform at TN=96) stage their output in
// the dead Al buffer (T[(c*4+n)*36+pl]) and write vt as coalesced 64B rows.
template <int MODE, int TN>
__global__ __launch_bounds__(256) void gemm_bt(const unsigned short* __restrict__ A,
                                               const unsigned short* __restrict__ Bw,
                                               const float* __restrict__ bias,
                                               const float* __restrict__ resid,
                                               void* __restrict__ Cout, int K, int N) {
  __shared__ unsigned short Al[2][128 * 64];
  __shared__ unsigned short Bl[2][TN * 64];
  constexpr int NI = TN / 32;
  int tid = threadIdx.x;
  int lane = tid & 63, w = tid >> 6;
  int q4 = lane >> 4, m16 = lane & 15;
  int m0 = blockIdx.x * 128, n0 = blockIdx.y * TN;
  int wm = (w >> 1) * 64, wn = (w & 1) * (TN / 2);
  facc zf = {0.f, 0.f, 0.f, 0.f};
  facc acc[4][NI];
#pragma unroll
  for (int mi = 0; mi < 4; ++mi)
#pragma unroll
    for (int ni = 0; ni < NI; ++ni) acc[mi][ni] = zf;

  int nt = K >> 6;

  auto stage = [&](int buf, int k0) {
#pragma unroll
    for (int i = 0; i < 4; ++i) {            // A: 128 rows x 8 chunks
      int F = i * 256 + tid;
      int r = F >> 3, j = F & 7, js = j ^ (r & 7);
      gl2lds16(A + (m0 + r) * K + k0 + js * 8, &Al[buf][F * 8]);
    }
#pragma unroll
    for (int i = 0; i < TN / 32; ++i) {      // B: TN rows x 8 chunks
      int F = i * 256 + tid;
      int r = F >> 3, j = F & 7, js = j ^ (r & 7);
      gl2lds16(Bw + (n0 + r) * K + k0 + js * 8, &Bl[buf][F * 8]);
    }
  };

  stage(0, 0);
  __syncthreads();

  for (int t = 0; t < nt; ++t) {
    int cur = t & 1;
    if (t + 1 < nt) stage(cur ^ 1, (t + 1) << 6);   // overlap with compute
#pragma unroll
    for (int ks = 0; ks < 2; ++ks) {
      bfrag a[4], bb[NI];
#pragma unroll
      for (int mi = 0; mi < 4; ++mi) {
        int row = wm + mi * 16 + m16;
        a[mi] = *(const bfrag*)&Al[cur][row * 64 + (((ks * 4 + q4) ^ (row & 7)) << 3)];
      }
#pragma unroll
      for (int ni = 0; ni < NI; ++ni) {
        int row = wn + ni * 16 + m16;
        bb[ni] = *(const bfrag*)&Bl[cur][row * 64 + (((ks * 4 + q4) ^ (row & 7)) << 3)];
      }
#pragma unroll
      for (int mi = 0; mi < 4; ++mi)
#pragma unroll
        for (int ni = 0; ni < NI; ++ni)
          acc[mi][ni] = mfma16(a[mi], bb[ni], acc[mi][ni]);
    }
    __syncthreads();   // drains next-tile staging; syncs buffer reuse
  }

  if constexpr (MODE == 3) {
    if (n0 >= 1536) {
      // ---- V third: LDS-staged transpose, coalesced 64B vt rows ----
      // thread value (mi,ni,r): n=r, dl = l-l0 = 16*(w>>1)+4*mi+q4 in [0,32),
      // pl = ((dl&15)<<1)|(dl>>4); p = l0+pl (bijective; l&32 block-constant).
      constexpr int P = 36;                  // padded row (8B-aligned, bank-spread)
      unsigned short* T = (unsigned short*)Al;   // 384*36*2 = 27.6KB < 32KB
      unsigned short* vtp = (unsigned short*)Cout;   // Cout = vt for MODE 3
#pragma unroll
      for (int mi = 0; mi < 4; ++mi) {
        int dl = 16 * (w >> 1) + 4 * mi + q4;
        int pl = ((dl & 15) << 1) | (dl >> 4);
#pragma unroll
        for (int ni = 0; ni < NI; ++ni) {
          int c = wn + ni * 16 + m16;        // local col 0..95
#pragma unroll
          for (int r = 0; r < 4; ++r) {
            float vv = acc[mi][ni][r] + bias[n0 + c];
            T[(c * 4 + r) * P + pl] = f2bf(vv);
          }
        }
      }
      __syncthreads();
      int l0 = m0 >> 2;
      int cb = n0 - 1536;
#pragma unroll
      for (int k = 0; k < 12; ++k) {         // 384 rows x 8 uint2 = 3072
        int idx = k * 256 + tid;
        int rr = idx >> 3, j = idx & 7;
        int c = cb + (rr >> 2), n = rr & 3;
        int by = ((c >> 6) << 2) | n, d = c & 63;
        *(uint2*)(vtp + ((size_t)by * 64 + d) * 2048 + l0 + j * 4) =
            *(const uint2*)&T[rr * P + j * 4];
      }
    } else {
      // ---- Q/K thirds: normal layout ----
#pragma unroll
      for (int mi = 0; mi < 4; ++mi)
#pragma unroll
        for (int ni = 0; ni < NI; ++ni)
#pragma unroll
          for (int r = 0; r < 4; ++r) {
            int row = m0 + wm + mi * 16 + q4 * 4 + r;
            int col = n0 + wn + ni * 16 + m16;
            ((unsigned short*)resid)[row * N + col] = f2bf(acc[mi][ni][r] + bias[col]);
          }
    }
    return;
  }

#pragma unroll
  for (int mi = 0; mi < 4; ++mi)
#pragma unroll
    for (int ni = 0; ni < NI; ++ni)
#pragma unroll
      for (int r = 0; r < 4; ++r) {
        int row = m0 + wm + mi * 16 + q4 * 4 + r;
        int col = n0 + wn + ni * 16 + m16;
        float vv = acc[mi][ni][r] + bias[col];
        if constexpr (MODE == 1) {
          ((float*)Cout)[row * N + col] = vv + resid[row * N + col];
        } else if constexpr (MODE == 2) {
          float g = vv / (1.f + __expf(-1.702f * vv));
          ((unsigned short*)Cout)[row * N + col] = f2bf(g);
        } else {
          ((unsigned short*)Cout)[row * N + col] = f2bf(vv);
        }
      }
}

// --------------------------- Flash attention --------------------------------
// grid (16 q-tiles of 128, 48 by=(h*4+n)), XCD-chunk-swizzled so each XCD
// owns 6 contiguous by values (K/V set 3MB fits per-XCD L2; FETCH
// 104.5->18.5MB verified). 4 waves, 32 q-rows each. Kl [kv][64] /
// Vtl [d][128] XOR-chunk-swizzled, async gl2lds staged: K(t+1) issued
// mid-tile, V(t+1) at tile end. P: per-wave private scratch, packed-pair
// b32 writes (interleaved k-order matching the MODE-3 vt layout).
__global__ __launch_bounds__(256) void flash_k(const unsigned short* __restrict__ qkv,
                                               const unsigned short* __restrict__ vt,
                                               unsigned short* __restrict__ o) {
  __shared__ unsigned short Kl[128 * 64];    // 16 KB
  __shared__ unsigned short Vtl[64 * 128];   // 16 KB
  __shared__ unsigned short Pp[4 * 32 * PW]; // 10 KB
  int tid = threadIdx.x;
  int lane = tid & 63, w = tid >> 6;
  int q4 = lane >> 4, m16 = lane & 15;

  // T1 chunked swizzle: 768 blocks, q=96; XCD k owns by in [6k, 6k+6)
  int idlin = blockIdx.x + blockIdx.y * 16;
  int wsw = (idlin & 7) * 96 + (idlin >> 3);
  int qt = wsw & 15;
  int by = wsw >> 4;

  int n = by & 3, h = by >> 2;
  const unsigned short* vtb = vt + (size_t)by * 64 * 2048;
  int wpb = w * 32 * PW;

  bfrag qf[2][2];
#pragma unroll
  for (int mi = 0; mi < 2; ++mi) {
    int l = qt * 128 + w * 32 + mi * 16 + m16;
#pragma unroll
    for (int ki = 0; ki < 2; ++ki)
      qf[mi][ki] = *(const bfrag*)(qkv + ((size_t)(l * 4 + n)) * 2304 + h * 64 + ki * 32 + q4 * 8);
  }

  facc zf = {0.f, 0.f, 0.f, 0.f};
  facc accO[2][4];
#pragma unroll
  for (int mi = 0; mi < 2; ++mi)
#pragma unroll
    for (int di = 0; di < 4; ++di) accO[mi][di] = zf;
  float lrow[2][4];
#pragma unroll
  for (int mi = 0; mi < 2; ++mi)
#pragma unroll
    for (int r = 0; r < 4; ++r) lrow[mi][r] = 0.f;

  const float cs = 0.125f * 1.44269504088896f;
  int ksw = m16 & 7;

#pragma unroll
  for (int i = 0; i < 4; ++i) {
    int F = i * 256 + tid;
    int r = F >> 3, ck = (F & 7) ^ (r & 7);
    gl2lds16(qkv + ((size_t)(r * 4 + n)) * 2304 + 768 + h * 64 + ck * 8, &Kl[F * 8]);
    int d = F >> 4, cv = (F & 15) ^ (d & 7);
    gl2lds16(vtb + d * 2048 + cv * 8, &Vtl[F * 8]);
  }
  __syncthreads();

  for (int kt = 0; kt < 16; ++kt) {
    facc S[2][8];
#pragma unroll
    for (int mi = 0; mi < 2; ++mi)
#pragma unroll
      for (int ni = 0; ni < 8; ++ni) S[mi][ni] = zf;
    __builtin_amdgcn_s_setprio(1);
#pragma unroll
    for (int ni = 0; ni < 8; ++ni)
#pragma unroll
      for (int ki = 0; ki < 2; ++ki) {
        bfrag bk = *(const bfrag*)&Kl[(ni * 16 + m16) * 64 + (((ki * 4 + q4) ^ ksw) << 3)];
#pragma unroll
        for (int mi = 0; mi < 2; ++mi)
          S[mi][ni] = mfma16(qf[mi][ki], bk, S[mi][ni]);
      }
    __builtin_amdgcn_s_setprio(0);
    __syncthreads();   // B: K reads done (also drains V(t) staging)

    if (kt < 15) {
      int kv0 = (kt + 1) * 128;
#pragma unroll
      for (int i = 0; i < 4; ++i) {
        int F = i * 256 + tid;
        int r = F >> 3, ck = (F & 7) ^ (r & 7);
        gl2lds16(qkv + ((size_t)((kv0 + r) * 4 + n)) * 2304 + 768 + h * 64 + ck * 8, &Kl[F * 8]);
      }
    }

#pragma unroll
    for (int si = 0; si < 4; ++si) {
#pragma unroll
      for (int mi = 0; mi < 2; ++mi)
#pragma unroll
        for (int r = 0; r < 4; ++r) {
          int prow = mi * 16 + q4 * 4 + r;
          float p0 = __builtin_amdgcn_exp2f(S[mi][2 * si][r] * cs);
          float p1 = __builtin_amdgcn_exp2f(S[mi][2 * si + 1][r] * cs);
          lrow[mi][r] += p0 + p1;
          // packed pair: storage col 2*m16 = logical kv m16 (p0),
          //              storage col 2*m16+1 = logical kv 16+m16 (p1)
          unsigned pk = (__float_as_uint(p0) >> 16) |
                        (__float_as_uint(p1) & 0xffff0000u);
          *(unsigned*)&Pp[wpb + prow * PW + 2 * m16] = pk;
        }
      bfrag pa[2];
#pragma unroll
      for (int mi = 0; mi < 2; ++mi)
        pa[mi] = *(const bfrag*)&Pp[wpb + (mi * 16 + m16) * PW + q4 * 8];
      __builtin_amdgcn_s_setprio(1);
#pragma unroll
      for (int di = 0; di < 4; ++di) {
        bfrag bv = *(const bfrag*)&Vtl[(di * 16 + m16) * 128 + (((si * 4 + q4) ^ ksw) << 3)];
#pragma unroll
        for (int mi = 0; mi < 2; ++mi)
          accO[mi][di] = mfma16(pa[mi], bv, accO[mi][di]);
      }
      __builtin_amdgcn_s_setprio(0);
    }
    __syncthreads();   // C: Vt reads done; K(t+1) staging drained here

    if (kt < 15) {
      int kv0 = (kt + 1) * 128;
#pragma unroll
      for (int i = 0; i < 4; ++i) {
        int F = i * 256 + tid;
        int d = F >> 4, cv = (F & 15) ^ (d & 7);
        gl2lds16(vtb + d * 2048 + kv0 + cv * 8, &Vtl[F * 8]);
      }
    }
  }

#pragma unroll
  for (int mi = 0; mi < 2; ++mi)
#pragma unroll
    for (int r = 0; r < 4; ++r) {
      float ls = lrow[mi][r];
      ls += __shfl_xor(ls, 1);
      ls += __shfl_xor(ls, 2);
      ls += __shfl_xor(ls, 4);
      ls += __shfl_xor(ls, 8);
      float inv = 1.f / ls;
      int l = qt * 128 + w * 32 + mi * 16 + q4 * 4 + r;
#pragma unroll
      for (int di = 0; di < 4; ++di) {
        int col = h * 64 + di * 16 + m16;
        o[(size_t)(l * 4 + n) * 768 + col] = f2bf(accO[mi][di][r] * inv);
      }
    }
}

// --------------------------- launcher ---------------------------------------
extern "C" void kernel_launch(void* const* d_in, const int* in_sizes, int n_in,
                              void* d_out, int out_size, void* d_ws, size_t ws_size,
                              hipStream_t stream) {
  (void)in_sizes; (void)n_in; (void)out_size; (void)ws_size;
  const float* x      = (const float*)d_in[0];
  const float* ln1_w  = (const float*)d_in[1];
  const float* ln1_b  = (const float*)d_in[2];
  const float* w_qkv  = (const float*)d_in[3];
  const float* b_qkv  = (const float*)d_in[4];
  const float* w_out  = (const float*)d_in[5];
  const float* b_out  = (const float*)d_in[6];
  const float* ln2_w  = (const float*)d_in[7];
  const float* ln2_b  = (const float*)d_in[8];
  const float* w_fc   = (const float*)d_in[9];
  const float* b_fc   = (const float*)d_in[10];
  const float* w_proj = (const float*)d_in[11];
  const float* b_proj = (const float*)d_in[12];

  char* ws = (char*)d_ws;
  unsigned short* qkv_bf  = (unsigned short*)(ws);
  unsigned short* o_bf    = (unsigned short*)(ws + 37748736);
  unsigned short* f_bf    = (unsigned short*)(ws);
  unsigned short* h_bf    = (unsigned short*)(ws + 50331648);
  float*          x1      = (float*)        (ws + 62914560);
  unsigned short* vt      = (unsigned short*)(ws + 62914560);  // dead before x1 written
  unsigned short* wqkv_bf = (unsigned short*)(ws + 88080384);
  unsigned short* wout_bf = (unsigned short*)(ws + 91619328);
  unsigned short* wfc_bf  = (unsigned short*)(ws + 92798976);
  unsigned short* wproj_bf= (unsigned short*)(ws + 97517568);

  head_k<<<8960, 256, 0, stream>>>(x, ln1_w, ln1_b, h_bf,
                                   w_qkv, w_out, w_fc, w_proj,
                                   wqkv_bf, wout_bf, wfc_bf, wproj_bf);
  // MODE 3: Cout = vt (V third, coalesced); resid slot = qkv_bf (Q/K thirds)
  gemm_bt<3, 96><<<dim3(64, 24), 256, 0, stream>>>(h_bf, wqkv_bf, b_qkv,
                                                   (const float*)qkv_bf, vt, 768, 2304);
  flash_k<<<dim3(16, 48), 256, 0, stream>>>(qkv_bf, vt, o_bf);
  gemm_bt<1, 96><<<dim3(64, 8), 256, 0, stream>>>(o_bf, wout_bf, b_out, x, x1, 768, 768);
  ln_bf16_k<<<2048, 256, 0, stream>>>(x1, ln2_w, ln2_b, h_bf);
  gemm_bt<2, 128><<<dim3(64, 24), 256, 0, stream>>>(h_bf, wfc_bf, b_fc, nullptr, f_bf, 768, 3072);
  gemm_bt<1, 96><<<dim3(64, 8), 256, 0, stream>>>(f_bf, wproj_bf, b_proj, x1, (float*)d_out, 3072, 768);
}

// Round 16
// 362.212 us; speedup vs baseline: 1.0158x; 1.0158x over previous
//
#include <hip/hip_runtime.h>

// ---------------------------------------------------------------------------
// ResidualAttentionBlock: LN1 -> QKV -> MHA(12 heads, Dh=64) -> out+res ->
//                         LN2 -> FC(4E)+QuickGELU -> proj+res
// R20 (final): R18 exact — the session-best verified configuration (366.0us;
//      430.7 -> 366.0, -15%). R19's TN=96 out/proj was clock-normalized
//      neutral -> reverted to TN=64. Components, each counter-verified:
//      - head_k: LN1 + weight-cast co-scheduled (one 8960-blk launch, -8us)
//      - QKV GEMM MODE 3: V-third written via LDS-staged transpose directly
//        to vt (coalesced 64B rows) — vtrans kernel deleted (+5us net)
//      - GEMMs: R9b 2-phase dbuf, TN 96/64/128/64, exact CU rounds
//        (6 structural variants ledger'd 375-390: structure-bound, not
//        barrier/tile/vmcnt-bound)
//      - flash_k: R13b staged loop + T1 XCD swizzle (FETCH 104.5->18.5MB;
//        95.5±1us x9 runs; conflicts 4718592 = structural gl2lds cost;
//        direct-global variant -2.1x, kv-split regressed — staged is optimal
//        at this wave structure)
// ---------------------------------------------------------------------------

#define E 768
#define LSEQ 2048
#define PW 40

typedef short bfrag __attribute__((ext_vector_type(8)));   // 8 bf16 = 4 VGPRs
typedef float facc  __attribute__((ext_vector_type(4)));   // 4 fp32 acc

__device__ __forceinline__ unsigned short f2bf(float f) {
  unsigned int u = __float_as_uint(f);
  u = (u + 0x7fffu + ((u >> 16) & 1u)) >> 16;   // RNE
  return (unsigned short)u;
}

__device__ __forceinline__ facc mfma16(bfrag a, bfrag b, facc c) {
  return __builtin_amdgcn_mfma_f32_16x16x32_bf16(a, b, c, 0, 0, 0);
}

__device__ __forceinline__ void gl2lds16(const void* g, void* l) {
  __builtin_amdgcn_global_load_lds((__attribute__((address_space(1))) void*)g,
                                   (__attribute__((address_space(3))) void*)l,
                                   16, 0, 0);
}

// --------------------------- fused head: LN1 + fp32->bf16 weight cast -------
// blocks [0,2048): LN1 rows (4 rows/block). blocks [2048,8960): weight cast,
// b2 = b-2048: [0,1728) w_qkv, [1728,2304) w_out, [2304,4608) w_fc,
// [4608,6912) w_proj. Independent work, both BW-bound -> co-scheduled.
__global__ __launch_bounds__(256) void head_k(const float* __restrict__ x,
                                              const float* __restrict__ lw,
                                              const float* __restrict__ lb,
                                              unsigned short* __restrict__ hout,
                                              const float* __restrict__ wq,
                                              const float* __restrict__ wo,
                                              const float* __restrict__ wf,
                                              const float* __restrict__ wp,
                                              unsigned short* __restrict__ d0,
                                              unsigned short* __restrict__ d1,
                                              unsigned short* __restrict__ d2,
                                              unsigned short* __restrict__ d3) {
  int b = blockIdx.x;
  if (b < 2048) {
    // ---- LN1 path ----
    int row = b * 4 + (threadIdx.x >> 6);
    int lane = threadIdx.x & 63;
    const float* xr = x + row * E;
    float4 v[3];
    float s = 0.f, ss = 0.f;
#pragma unroll
    for (int i = 0; i < 3; ++i) {
      v[i] = *(const float4*)(xr + i * 256 + lane * 4);
      s += v[i].x + v[i].y + v[i].z + v[i].w;
      ss += v[i].x * v[i].x + v[i].y * v[i].y + v[i].z * v[i].z + v[i].w * v[i].w;
    }
#pragma unroll
    for (int m = 32; m; m >>= 1) { s += __shfl_xor(s, m); ss += __shfl_xor(ss, m); }
    float mu = s * (1.f / E);
    float rstd = rsqrtf(ss * (1.f / E) - mu * mu + 1e-5f);
#pragma unroll
    for (int i = 0; i < 3; ++i) {
      int c = i * 256 + lane * 4;
      float4 wv = *(const float4*)(lw + c);
      float4 bv = *(const float4*)(lb + c);
      float y0 = (v[i].x - mu) * rstd * wv.x + bv.x;
      float y1 = (v[i].y - mu) * rstd * wv.y + bv.y;
      float y2 = (v[i].z - mu) * rstd * wv.z + bv.z;
      float y3 = (v[i].w - mu) * rstd * wv.w + bv.w;
      uint2 o;
      o.x = (unsigned)f2bf(y0) | ((unsigned)f2bf(y1) << 16);
      o.y = (unsigned)f2bf(y2) | ((unsigned)f2bf(y3) << 16);
      *(uint2*)(hout + row * E + c) = o;
    }
  } else {
    // ---- weight-cast path ----
    int b2 = b - 2048;
    const float* s; unsigned short* d; int off;
    if (b2 < 1728)      { s = wq; d = d0; off = b2; }
    else if (b2 < 2304) { s = wo; d = d1; off = b2 - 1728; }
    else if (b2 < 4608) { s = wf; d = d2; off = b2 - 2304; }
    else                { s = wp; d = d3; off = b2 - 4608; }
    int i = (off * 256 + threadIdx.x) * 4;
    float4 v = *(const float4*)(s + i);
    uint2 u;
    u.x = (unsigned)f2bf(v.x) | ((unsigned)f2bf(v.y) << 16);
    u.y = (unsigned)f2bf(v.z) | ((unsigned)f2bf(v.w) << 16);
    *(uint2*)(d + i) = u;
  }
}

// --------------------------- LayerNorm (fp32 in, bf16 out) — LN2 ------------
__global__ __launch_bounds__(256) void ln_bf16_k(const float* __restrict__ x,
                                                 const float* __restrict__ w,
                                                 const float* __restrict__ b,
                                                 unsigned short* __restrict__ out) {
  int row = blockIdx.x * 4 + (threadIdx.x >> 6);
  int lane = threadIdx.x & 63;
  const float* xr = x + row * E;
  float4 v[3];
  float s = 0.f, ss = 0.f;
#pragma unroll
  for (int i = 0; i < 3; ++i) {
    v[i] = *(const float4*)(xr + i * 256 + lane * 4);
    s += v[i].x + v[i].y + v[i].z + v[i].w;
    ss += v[i].x * v[i].x + v[i].y * v[i].y + v[i].z * v[i].z + v[i].w * v[i].w;
  }
#pragma unroll
  for (int m = 32; m; m >>= 1) { s += __shfl_xor(s, m); ss += __shfl_xor(ss, m); }
  float mu = s * (1.f / E);
  float rstd = rsqrtf(ss * (1.f / E) - mu * mu + 1e-5f);
#pragma unroll
  for (int i = 0; i < 3; ++i) {
    int c = i * 256 + lane * 4;
    float4 wv = *(const float4*)(w + c);
    float4 bv = *(const float4*)(b + c);
    float y0 = (v[i].x - mu) * rstd * wv.x + bv.x;
    float y1 = (v[i].y - mu) * rstd * wv.y + bv.y;
    float y2 = (v[i].z - mu) * rstd * wv.z + bv.z;
    float y3 = (v[i].w - mu) * rstd * wv.w + bv.w;
    uint2 o;
    o.x = (unsigned)f2bf(y0) | ((unsigned)f2bf(y1) << 16);
    o.y = (unsigned)f2bf(y2) | ((unsigned)f2bf(y3) << 16);
    *(uint2*)(out + row * E + c) = o;
  }
}

// --------------------------- GEMM: C[M,N] = A[M,K] * W[N,K]^T + epilogue ----
// TM=128, BK=64, double-buffered LDS, 2-phase pipeline. MODE 3 (QKV):
// V-third blocks (n0>=1536, block-uniform at TN=96) stage their output in
// the dead Al buffer (T[(c*4+n)*36+pl]) and write vt as coalesced 64B rows.
template <int MODE, int TN>
__global__ __launch_bounds__(256) void gemm_bt(const unsigned short* __restrict__ A,
                                               const unsigned short* __restrict__ Bw,
                                               const float* __restrict__ bias,
                                               const float* __restrict__ resid,
                                               void* __restrict__ Cout, int K, int N) {
  __shared__ unsigned short Al[2][128 * 64];
  __shared__ unsigned short Bl[2][TN * 64];
  constexpr int NI = TN / 32;
  int tid = threadIdx.x;
  int lane = tid & 63, w = tid >> 6;
  int q4 = lane >> 4, m16 = lane & 15;
  int m0 = blockIdx.x * 128, n0 = blockIdx.y * TN;
  int wm = (w >> 1) * 64, wn = (w & 1) * (TN / 2);
  facc zf = {0.f, 0.f, 0.f, 0.f};
  facc acc[4][NI];
#pragma unroll
  for (int mi = 0; mi < 4; ++mi)
#pragma unroll
    for (int ni = 0; ni < NI; ++ni) acc[mi][ni] = zf;

  int nt = K >> 6;

  auto stage = [&](int buf, int k0) {
#pragma unroll
    for (int i = 0; i < 4; ++i) {            // A: 128 rows x 8 chunks
      int F = i * 256 + tid;
      int r = F >> 3, j = F & 7, js = j ^ (r & 7);
      gl2lds16(A + (m0 + r) * K + k0 + js * 8, &Al[buf][F * 8]);
    }
#pragma unroll
    for (int i = 0; i < TN / 32; ++i) {      // B: TN rows x 8 chunks
      int F = i * 256 + tid;
      int r = F >> 3, j = F & 7, js = j ^ (r & 7);
      gl2lds16(Bw + (n0 + r) * K + k0 + js * 8, &Bl[buf][F * 8]);
    }
  };

  stage(0, 0);
  __syncthreads();

  for (int t = 0; t < nt; ++t) {
    int cur = t & 1;
    if (t + 1 < nt) stage(cur ^ 1, (t + 1) << 6);   // overlap with compute
#pragma unroll
    for (int ks = 0; ks < 2; ++ks) {
      bfrag a[4], bb[NI];
#pragma unroll
      for (int mi = 0; mi < 4; ++mi) {
        int row = wm + mi * 16 + m16;
        a[mi] = *(const bfrag*)&Al[cur][row * 64 + (((ks * 4 + q4) ^ (row & 7)) << 3)];
      }
#pragma unroll
      for (int ni = 0; ni < NI; ++ni) {
        int row = wn + ni * 16 + m16;
        bb[ni] = *(const bfrag*)&Bl[cur][row * 64 + (((ks * 4 + q4) ^ (row & 7)) << 3)];
      }
#pragma unroll
      for (int mi = 0; mi < 4; ++mi)
#pragma unroll
        for (int ni = 0; ni < NI; ++ni)
          acc[mi][ni] = mfma16(a[mi], bb[ni], acc[mi][ni]);
    }
    __syncthreads();   // drains next-tile staging; syncs buffer reuse
  }

  if constexpr (MODE == 3) {
    if (n0 >= 1536) {
      // ---- V third: LDS-staged transpose, coalesced 64B vt rows ----
      // thread value (mi,ni,r): n=r, dl = l-l0 = 16*(w>>1)+4*mi+q4 in [0,32),
      // pl = ((dl&15)<<1)|(dl>>4); p = l0+pl (bijective; l&32 block-constant).
      constexpr int P = 36;                  // padded row (8B-aligned, bank-spread)
      unsigned short* T = (unsigned short*)Al;   // 384*36*2 = 27.6KB < 32KB
      unsigned short* vtp = (unsigned short*)Cout;   // Cout = vt for MODE 3
#pragma unroll
      for (int mi = 0; mi < 4; ++mi) {
        int dl = 16 * (w >> 1) + 4 * mi + q4;
        int pl = ((dl & 15) << 1) | (dl >> 4);
#pragma unroll
        for (int ni = 0; ni < NI; ++ni) {
          int c = wn + ni * 16 + m16;        // local col 0..95
#pragma unroll
          for (int r = 0; r < 4; ++r) {
            float vv = acc[mi][ni][r] + bias[n0 + c];
            T[(c * 4 + r) * P + pl] = f2bf(vv);
          }
        }
      }
      __syncthreads();
      int l0 = m0 >> 2;
      int cb = n0 - 1536;
#pragma unroll
      for (int k = 0; k < 12; ++k) {         // 384 rows x 8 uint2 = 3072
        int idx = k * 256 + tid;
        int rr = idx >> 3, j = idx & 7;
        int c = cb + (rr >> 2), n = rr & 3;
        int by = ((c >> 6) << 2) | n, d = c & 63;
        *(uint2*)(vtp + ((size_t)by * 64 + d) * 2048 + l0 + j * 4) =
            *(const uint2*)&T[rr * P + j * 4];
      }
    } else {
      // ---- Q/K thirds: normal layout ----
#pragma unroll
      for (int mi = 0; mi < 4; ++mi)
#pragma unroll
        for (int ni = 0; ni < NI; ++ni)
#pragma unroll
          for (int r = 0; r < 4; ++r) {
            int row = m0 + wm + mi * 16 + q4 * 4 + r;
            int col = n0 + wn + ni * 16 + m16;
            ((unsigned short*)resid)[row * N + col] = f2bf(acc[mi][ni][r] + bias[col]);
          }
    }
    return;
  }

#pragma unroll
  for (int mi = 0; mi < 4; ++mi)
#pragma unroll
    for (int ni = 0; ni < NI; ++ni)
#pragma unroll
      for (int r = 0; r < 4; ++r) {
        int row = m0 + wm + mi * 16 + q4 * 4 + r;
        int col = n0 + wn + ni * 16 + m16;
        float vv = acc[mi][ni][r] + bias[col];
        if constexpr (MODE == 1) {
          ((float*)Cout)[row * N + col] = vv + resid[row * N + col];
        } else if constexpr (MODE == 2) {
          float g = vv / (1.f + __expf(-1.702f * vv));
          ((unsigned short*)Cout)[row * N + col] = f2bf(g);
        } else {
          ((unsigned short*)Cout)[row * N + col] = f2bf(vv);
        }
      }
}

// --------------------------- Flash attention --------------------------------
// grid (16 q-tiles of 128, 48 by=(h*4+n)), XCD-chunk-swizzled so each XCD
// owns 6 contiguous by values (K/V set 3MB fits per-XCD L2; FETCH
// 104.5->18.5MB verified). 4 waves, 32 q-rows each. Kl [kv][64] /
// Vtl [d][128] XOR-chunk-swizzled, async gl2lds staged: K(t+1) issued
// mid-tile, V(t+1) at tile end. P: per-wave private scratch, packed-pair
// b32 writes (interleaved k-order matching the MODE-3 vt layout).
__global__ __launch_bounds__(256) void flash_k(const unsigned short* __restrict__ qkv,
                                               const unsigned short* __restrict__ vt,
                                               unsigned short* __restrict__ o) {
  __shared__ unsigned short Kl[128 * 64];    // 16 KB
  __shared__ unsigned short Vtl[64 * 128];   // 16 KB
  __shared__ unsigned short Pp[4 * 32 * PW]; // 10 KB
  int tid = threadIdx.x;
  int lane = tid & 63, w = tid >> 6;
  int q4 = lane >> 4, m16 = lane & 15;

  // T1 chunked swizzle: 768 blocks, q=96; XCD k owns by in [6k, 6k+6)
  int idlin = blockIdx.x + blockIdx.y * 16;
  int wsw = (idlin & 7) * 96 + (idlin >> 3);
  int qt = wsw & 15;
  int by = wsw >> 4;

  int n = by & 3, h = by >> 2;
  const unsigned short* vtb = vt + (size_t)by * 64 * 2048;
  int wpb = w * 32 * PW;

  bfrag qf[2][2];
#pragma unroll
  for (int mi = 0; mi < 2; ++mi) {
    int l = qt * 128 + w * 32 + mi * 16 + m16;
#pragma unroll
    for (int ki = 0; ki < 2; ++ki)
      qf[mi][ki] = *(const bfrag*)(qkv + ((size_t)(l * 4 + n)) * 2304 + h * 64 + ki * 32 + q4 * 8);
  }

  facc zf = {0.f, 0.f, 0.f, 0.f};
  facc accO[2][4];
#pragma unroll
  for (int mi = 0; mi < 2; ++mi)
#pragma unroll
    for (int di = 0; di < 4; ++di) accO[mi][di] = zf;
  float lrow[2][4];
#pragma unroll
  for (int mi = 0; mi < 2; ++mi)
#pragma unroll
    for (int r = 0; r < 4; ++r) lrow[mi][r] = 0.f;

  const float cs = 0.125f * 1.44269504088896f;
  int ksw = m16 & 7;

#pragma unroll
  for (int i = 0; i < 4; ++i) {
    int F = i * 256 + tid;
    int r = F >> 3, ck = (F & 7) ^ (r & 7);
    gl2lds16(qkv + ((size_t)(r * 4 + n)) * 2304 + 768 + h * 64 + ck * 8, &Kl[F * 8]);
    int d = F >> 4, cv = (F & 15) ^ (d & 7);
    gl2lds16(vtb + d * 2048 + cv * 8, &Vtl[F * 8]);
  }
  __syncthreads();

  for (int kt = 0; kt < 16; ++kt) {
    facc S[2][8];
#pragma unroll
    for (int mi = 0; mi < 2; ++mi)
#pragma unroll
      for (int ni = 0; ni < 8; ++ni) S[mi][ni] = zf;
    __builtin_amdgcn_s_setprio(1);
#pragma unroll
    for (int ni = 0; ni < 8; ++ni)
#pragma unroll
      for (int ki = 0; ki < 2; ++ki) {
        bfrag bk = *(const bfrag*)&Kl[(ni * 16 + m16) * 64 + (((ki * 4 + q4) ^ ksw) << 3)];
#pragma unroll
        for (int mi = 0; mi < 2; ++mi)
          S[mi][ni] = mfma16(qf[mi][ki], bk, S[mi][ni]);
      }
    __builtin_amdgcn_s_setprio(0);
    __syncthreads();   // B: K reads done (also drains V(t) staging)

    if (kt < 15) {
      int kv0 = (kt + 1) * 128;
#pragma unroll
      for (int i = 0; i < 4; ++i) {
        int F = i * 256 + tid;
        int r = F >> 3, ck = (F & 7) ^ (r & 7);
        gl2lds16(qkv + ((size_t)((kv0 + r) * 4 + n)) * 2304 + 768 + h * 64 + ck * 8, &Kl[F * 8]);
      }
    }

#pragma unroll
    for (int si = 0; si < 4; ++si) {
#pragma unroll
      for (int mi = 0; mi < 2; ++mi)
#pragma unroll
        for (int r = 0; r < 4; ++r) {
          int prow = mi * 16 + q4 * 4 + r;
          float p0 = __builtin_amdgcn_exp2f(S[mi][2 * si][r] * cs);
          float p1 = __builtin_amdgcn_exp2f(S[mi][2 * si + 1][r] * cs);
          lrow[mi][r] += p0 + p1;
          // packed pair: storage col 2*m16 = logical kv m16 (p0),
          //              storage col 2*m16+1 = logical kv 16+m16 (p1)
          unsigned pk = (__float_as_uint(p0) >> 16) |
                        (__float_as_uint(p1) & 0xffff0000u);
          *(unsigned*)&Pp[wpb + prow * PW + 2 * m16] = pk;
        }
      bfrag pa[2];
#pragma unroll
      for (int mi = 0; mi < 2; ++mi)
        pa[mi] = *(const bfrag*)&Pp[wpb + (mi * 16 + m16) * PW + q4 * 8];
      __builtin_amdgcn_s_setprio(1);
#pragma unroll
      for (int di = 0; di < 4; ++di) {
        bfrag bv = *(const bfrag*)&Vtl[(di * 16 + m16) * 128 + (((si * 4 + q4) ^ ksw) << 3)];
#pragma unroll
        for (int mi = 0; mi < 2; ++mi)
          accO[mi][di] = mfma16(pa[mi], bv, accO[mi][di]);
      }
      __builtin_amdgcn_s_setprio(0);
    }
    __syncthreads();   // C: Vt reads done; K(t+1) staging drained here

    if (kt < 15) {
      int kv0 = (kt + 1) * 128;
#pragma unroll
      for (int i = 0; i < 4; ++i) {
        int F = i * 256 + tid;
        int d = F >> 4, cv = (F & 15) ^ (d & 7);
        gl2lds16(vtb + d * 2048 + kv0 + cv * 8, &Vtl[F * 8]);
      }
    }
  }

#pragma unroll
  for (int mi = 0; mi < 2; ++mi)
#pragma unroll
    for (int r = 0; r < 4; ++r) {
      float ls = lrow[mi][r];
      ls += __shfl_xor(ls, 1);
      ls += __shfl_xor(ls, 2);
      ls += __shfl_xor(ls, 4);
      ls += __shfl_xor(ls, 8);
      float inv = 1.f / ls;
      int l = qt * 128 + w * 32 + mi * 16 + q4 * 4 + r;
#pragma unroll
      for (int di = 0; di < 4; ++di) {
        int col = h * 64 + di * 16 + m16;
        o[(size_t)(l * 4 + n) * 768 + col] = f2bf(accO[mi][di][r] * inv);
      }
    }
}

// --------------------------- launcher ---------------------------------------
extern "C" void kernel_launch(void* const* d_in, const int* in_sizes, int n_in,
                              void* d_out, int out_size, void* d_ws, size_t ws_size,
                              hipStream_t stream) {
  (void)in_sizes; (void)n_in; (void)out_size; (void)ws_size;
  const float* x      = (const float*)d_in[0];
  const float* ln1_w  = (const float*)d_in[1];
  const float* ln1_b  = (const float*)d_in[2];
  const float* w_qkv  = (const float*)d_in[3];
  const float* b_qkv  = (const float*)d_in[4];
  const float* w_out  = (const float*)d_in[5];
  const float* b_out  = (const float*)d_in[6];
  const float* ln2_w  = (const float*)d_in[7];
  const float* ln2_b  = (const float*)d_in[8];
  const float* w_fc   = (const float*)d_in[9];
  const float* b_fc   = (const float*)d_in[10];
  const float* w_proj = (const float*)d_in[11];
  const float* b_proj = (const float*)d_in[12];

  char* ws = (char*)d_ws;
  unsigned short* qkv_bf  = (unsigned short*)(ws);
  unsigned short* o_bf    = (unsigned short*)(ws + 37748736);
  unsigned short* f_bf    = (unsigned short*)(ws);
  unsigned short* h_bf    = (unsigned short*)(ws + 50331648);
  float*          x1      = (float*)        (ws + 62914560);
  unsigned short* vt      = (unsigned short*)(ws + 62914560);  // dead before x1 written
  unsigned short* wqkv_bf = (unsigned short*)(ws + 88080384);
  unsigned short* wout_bf = (unsigned short*)(ws + 91619328);
  unsigned short* wfc_bf  = (unsigned short*)(ws + 92798976);
  unsigned short* wproj_bf= (unsigned short*)(ws + 97517568);

  head_k<<<8960, 256, 0, stream>>>(x, ln1_w, ln1_b, h_bf,
                                   w_qkv, w_out, w_fc, w_proj,
                                   wqkv_bf, wout_bf, wfc_bf, wproj_bf);
  // MODE 3: Cout = vt (V third, coalesced); resid slot = qkv_bf (Q/K thirds)
  gemm_bt<3, 96><<<dim3(64, 24), 256, 0, stream>>>(h_bf, wqkv_bf, b_qkv,
                                                   (const float*)qkv_bf, vt, 768, 2304);
  flash_k<<<dim3(16, 48), 256, 0, stream>>>(qkv_bf, vt, o_bf);
  gemm_bt<1, 64><<<dim3(64, 12), 256, 0, stream>>>(o_bf, wout_bf, b_out, x, x1, 768, 768);
  ln_bf16_k<<<2048, 256, 0, stream>>>(x1, ln2_w, ln2_b, h_bf);
  gemm_bt<2, 128><<<dim3(64, 24), 256, 0, stream>>>(h_bf, wfc_bf, b_fc, nullptr, f_bf, 768, 3072);
  gemm_bt<1, 64><<<dim3(64, 12), 256, 0, stream>>>(f_bf, wproj_bf, b_proj, x1, (float*)d_out, 3072, 768);
}